// Round 8
// baseline (640.207 us; speedup 1.0000x reference)
//
#include <hip/hip_runtime.h>

// Conv 7x7, 256 in-ch, 1 out-ch, valid -> (16,218,218), via bf16 MFMA + Toeplitz B.
// out[h0+mm][w0+j] = sum_{c,kh,s} A[mm][kk] * B[kk][j],  kk = kh*24 + s (pad to 192)
// Round 8: R7 + ONE change: 2-deep register prefetch. Two named staging sets
// (xa0/xb0, xa1/xb1), channel loop unrolled x2 (set & LDS-buf indices are
// compile-time -> no scratch). Loads for channel cc+2 issue at cc; the wait
// before stage_store is on 2-iteration-old loads (vmcnt(~22), ~free) instead
// of draining the VMEM queue to zero every iteration (T4: counted, never 0).

#define C_IN 256
#define Hd 224
#define Wd 224
#define OHd 218
#define OWd 218
#define KS 7

#define NSPLIT 8
#define CPB (C_IN / NSPLIT)     // 32 channels per block
#define TH 32                   // output rows per block (2 MFMA m-tiles)
#define NHB 7                   // h-bands: h0 = 0,32,...,160,186
#define NCHUNK 6                // K-chunks of 32 per channel (kh*24+s, 192 padded)
#define PITCH 232               // LDS row pitch (bf16); 464B rows, bank-stride 20
#define SROWS 38                // staged rows per band (TH + 6)
#define TROWS 40                // + 2 zero pad rows (A reads reach row 38)
#define LDSE (TROWS * PITCH)    // ushorts per buffer
#define NTHREADS 256
#define NSLOTS (SROWS * 28)     // 1064 stage slots (28 x 8-float groups per row)
#define NBLOCKS (16 * NHB * NSPLIT)   // 896 = 8 XCDs x 112

typedef short s16x8 __attribute__((ext_vector_type(8)));
typedef float f32x4 __attribute__((ext_vector_type(4)));

__device__ __forceinline__ unsigned short f2bf(float f) {
  unsigned int u = __float_as_uint(f);
  u = (u + 0x7FFFu + ((u >> 16) & 1u)) >> 16;   // RNE truncate to bf16
  return (unsigned short)u;
}

__global__ __launch_bounds__(256) void init_out_kernel(float* __restrict__ out,
                                                       const float* __restrict__ bias,
                                                       int n) {
  int i = blockIdx.x * 256 + threadIdx.x;
  if (i < n) out[i] = bias[0];
}

// Build Toeplitz B in fragment order: bws[((c*6+t)*64+l)*8+e] = B[kk(t,l,e)][j(l)]
__global__ __launch_bounds__(256) void build_b_kernel(const float* __restrict__ w,
                                                      unsigned short* __restrict__ bws) {
  int i = blockIdx.x * 256 + threadIdx.x;
  if (i >= C_IN * NCHUNK * 64) return;
  int l = i & 63;
  int t = (i >> 6) % NCHUNK;
  int c = i / (NCHUNK * 64);
  int q = l >> 4, j = l & 15;
  unsigned short v[8];
  #pragma unroll
  for (int e = 0; e < 8; ++e) {
    int kk = t * 32 + q * 8 + e;
    int kh = kk / 24, s = kk - kh * 24;
    int kw = s - j;
    float val = (kh < KS && kw >= 0 && kw < KS) ? w[(c * KS + kh) * KS + kw] : 0.f;
    v[e] = f2bf(val);
  }
  uint4 pk;
  pk.x = (unsigned)v[0] | ((unsigned)v[1] << 16);
  pk.y = (unsigned)v[2] | ((unsigned)v[3] << 16);
  pk.z = (unsigned)v[4] | ((unsigned)v[5] << 16);
  pk.w = (unsigned)v[6] | ((unsigned)v[7] << 16);
  *reinterpret_cast<uint4*>(bws + (size_t)i * 8) = pk;
}

__global__ __launch_bounds__(NTHREADS, 3) void conv_mfma_kernel(
    const float* __restrict__ x, const unsigned short* __restrict__ bws,
    float* __restrict__ out) {
  __shared__ unsigned short tile[2][LDSE];

  const int tid = threadIdx.x;
  const int bid = blockIdx.x;
  // XCD swizzle: HW XCD = bid%8. XCD g owns 16 (b,cs) pairs, all 7 bands each.
  const int g    = bid & 7;
  const int slot = bid >> 3;       // 0..111
  const int hb   = slot % NHB;     // 0..6
  const int pl   = slot / NHB;     // 0..15
  const int pc   = g * 16 + pl;    // 0..127 = b*NSPLIT + cs
  const int cs   = pc & (NSPLIT - 1);
  const int b    = pc >> 3;
  const int h0 = (hb == NHB - 1) ? (OHd - TH) : hb * TH;   // 186 at edge
  const int c0 = cs * CPB;
  // owner rows (disjoint partition so the overlapped last band doesn't double-add)
  const int rlo = (hb == NHB - 1) ? (NHB - 1) * TH : h0;   // 192 at edge
  const int rhi = (hb == NHB - 1) ? OHd : h0 + TH;

  const int ln = tid & 63;
  const int wv = tid >> 6;      // 4 waves
  const int mt = wv & 1;        // m-tile (rows h0+mt*16 .. +15)
  const int jh = wv >> 1;       // j-half: tiles [jh*7, jh*7+7)
  const int q  = ln >> 4;
  const int m  = ln & 15;

  // per-chunk A byte offsets within a buffer: row (mt*16+m+kh0), col s0
  int aoff[NCHUNK];
  #pragma unroll
  for (int t = 0; t < NCHUNK; ++t) {
    int k0 = t * 32 + q * 8;
    int kh0 = k0 / 24;
    int s0 = k0 - kh0 * 24;
    aoff[t] = (mt * 16 + m + kh0) * (PITCH * 2) + s0 * 2;
  }

  // staging slots: 38 rows x 28 (16B bf16 groups) = 1064 slots over 256 threads
  int goff[5]; int wboff[5]; bool sval[5];
  #pragma unroll
  for (int i = 0; i < 5; ++i) {
    int f = tid + NTHREADS * i;
    sval[i] = (f < NSLOTS);
    int r = sval[i] ? (f / 28) : 0;
    int cg = sval[i] ? (f - r * 28) : 0;
    int rg = h0 + r; if (rg > Hd - 1) rg = Hd - 1;
    goff[i]  = rg * Wd + cg * 8;
    wboff[i] = r * (PITCH * 2) + cg * 16;
  }

  const float* xplane = x + (size_t)(b * C_IN + c0) * (Hd * Wd);

  float4 xa0[5], xb0[5], xa1[5], xb1[5];   // two named prefetch sets

#define STAGE_ISSUE(SET, CCH) do {                                          \
    const float* xn_ = xplane + (size_t)(CCH) * (Hd * Wd);                  \
    _Pragma("unroll")                                                       \
    for (int i_ = 0; i_ < 5; ++i_) if (sval[i_]) {                          \
      xa##SET[i_] = *reinterpret_cast<const float4*>(xn_ + goff[i_]);       \
      xb##SET[i_] = *reinterpret_cast<const float4*>(xn_ + goff[i_] + 4);   \
    }                                                                       \
  } while (0)

#define STAGE_STORE(SET, BUF) do {                                          \
    _Pragma("unroll")                                                       \
    for (int i_ = 0; i_ < 5; ++i_) if (sval[i_]) {                          \
      s16x8 v_;                                                             \
      v_[0] = (short)f2bf(xa##SET[i_].x); v_[1] = (short)f2bf(xa##SET[i_].y); \
      v_[2] = (short)f2bf(xa##SET[i_].z); v_[3] = (short)f2bf(xa##SET[i_].w); \
      v_[4] = (short)f2bf(xb##SET[i_].x); v_[5] = (short)f2bf(xb##SET[i_].y); \
      v_[6] = (short)f2bf(xb##SET[i_].z); v_[7] = (short)f2bf(xb##SET[i_].w); \
      *reinterpret_cast<s16x8*>(reinterpret_cast<char*>(&tile[BUF][0]) + wboff[i_]) = v_; \
    }                                                                       \
  } while (0)

#define COMPUTE(BUF, BFR) do {                                              \
    const char* base_ = reinterpret_cast<const char*>(&tile[BUF][0]);       \
    _Pragma("unroll")                                                       \
    for (int jj_ = 0; jj_ < 7; ++jj_) {                                     \
      const int cb_ = (jh * 7 + jj_) * 32;                                  \
      _Pragma("unroll")                                                     \
      for (int t_ = 0; t_ < NCHUNK; ++t_) {                                 \
        s16x8 a_ = *reinterpret_cast<const s16x8*>(base_ + (aoff[t_] + cb_)); \
        acc[jj_] = __builtin_amdgcn_mfma_f32_16x16x32_bf16(a_, BFR[t_], acc[jj_], 0, 0, 0); \
      }                                                                     \
    }                                                                       \
  } while (0)

  // issue prefetch for channels 0 and 1 ASAP (overlaps LDS zero-init)
  STAGE_ISSUE(0, 0);
  STAGE_ISSUE(1, 1);

  // zero all of LDS once: pad rows/cols must stay finite-zero forever
  {
    uint4 z; z.x = z.y = z.z = z.w = 0u;
    for (int i = tid; i < 2 * LDSE / 8; i += NTHREADS)
      reinterpret_cast<uint4*>(&tile[0][0])[i] = z;
  }

  f32x4 acc[7];
  #pragma unroll
  for (int jj = 0; jj < 7; ++jj) acc[jj] = (f32x4){0.f, 0.f, 0.f, 0.f};

  __syncthreads();   // zero-init visible before first ds_write

  for (int cc = 0; cc < CPB; cc += 2) {
    { // half 0: channel cc, LDS buf 0, reg set 0
      s16x8 bfr[NCHUNK];
      const unsigned short* bp = bws + ((size_t)(c0 + cc) * NCHUNK * 64 + ln) * 8;
      #pragma unroll
      for (int t = 0; t < NCHUNK; ++t)
        bfr[t] = *reinterpret_cast<const s16x8*>(bp + t * 512);
      STAGE_STORE(0, 0);                     // waits only on set-0 loads (2 iters old)
      if (cc + 2 < CPB) STAGE_ISSUE(0, cc + 2);
      __syncthreads();
      COMPUTE(0, bfr);
    }
    { // half 1: channel cc+1, LDS buf 1, reg set 1
      s16x8 bfr[NCHUNK];
      const unsigned short* bp = bws + ((size_t)(c0 + cc + 1) * NCHUNK * 64 + ln) * 8;
      #pragma unroll
      for (int t = 0; t < NCHUNK; ++t)
        bfr[t] = *reinterpret_cast<const s16x8*>(bp + t * 512);
      STAGE_STORE(1, 1);
      if (cc + 3 < CPB) STAGE_ISSUE(1, cc + 3);
      __syncthreads();
      COMPUTE(1, bfr);
    }
  }

  // D layout: col = lane&15, row = (lane>>4)*4 + reg
  const size_t ob = (size_t)b * (OHd * OWd);
  const int oh_base = h0 + mt * 16 + q * 4;
  #pragma unroll
  for (int jj = 0; jj < 7; ++jj) {
    const int ow = (jh * 7 + jj) * 16 + m;
    if (ow < OWd) {
      #pragma unroll
      for (int r = 0; r < 4; ++r) {
        const int oh = oh_base + r;
        if (oh >= rlo && oh < rhi)
          atomicAdd(out + ob + (size_t)oh * OWd + ow, acc[jj][r]);
      }
    }
  }
#undef STAGE_ISSUE
#undef STAGE_STORE
#undef COMPUTE
}

extern "C" void kernel_launch(void* const* d_in, const int* in_sizes, int n_in,
                              void* d_out, int out_size, void* d_ws, size_t ws_size,
                              hipStream_t stream) {
  const float* x    = (const float*)d_in[0];
  const float* w    = (const float*)d_in[1];
  const float* bias = (const float*)d_in[2];
  float* out        = (float*)d_out;
  unsigned short* bws = (unsigned short*)d_ws;   // needs 1.57 MB

  init_out_kernel<<<(out_size + 255) / 256, 256, 0, stream>>>(out, bias, out_size);
  build_b_kernel<<<(C_IN * NCHUNK * 64 + 255) / 256, 256, 0, stream>>>(w, bws);
  conv_mfma_kernel<<<NBLOCKS, NTHREADS, 0, stream>>>(x, bws, out);
}

// Round 10
// 186.790 us; speedup vs baseline: 3.4274x; 3.4274x over previous
//
#include <hip/hip_runtime.h>

// Conv 7x7, 256 in-ch, 1 out-ch, valid -> (16,218,218), via bf16 MFMA + Toeplitz B.
// out[h0+m][w0+j] = sum_{c,kh,s} A[m][kk] * B[kk][j],  kk = kh*24 + s (pad to 192)
// Round 10 = R6 (proven 196.5us; TH=16, NSPLIT=4, 128 thr, XCD swizzle, TROWS=24)
// + ONE change: fp32->bf16 via inline-asm v_cvt_pk_bf16_f32 (HW RNE, 1 instr/2
// elems) instead of 3-VALU integer RNE (120->20 VALU per staging iteration).
// R9's NaN was TROWS=22: chunk t=5/q>=1 has kh0=7 (zero-B pad) -> A reads row
// m+7=22; buffer-1 row 22 must exist and be zero. TROWS=24 restored.

#define C_IN 256
#define Hd 224
#define Wd 224
#define OHd 218
#define OWd 218
#define KS 7

#define NSPLIT 4
#define CPB (C_IN / NSPLIT)     // 64 channels per block
#define TH 16                   // output rows per block
#define NHB 14                  // h-bands
#define NCHUNK 6                // K-chunks of 32 per channel (kh*24+s, 192 padded)
#define PITCH 232               // LDS row pitch (bf16); cols 224..231 stay zero
#define TROWS 24                // 22 staged rows + 2 zero pad rows (reads reach row 22)
#define LDSE (TROWS * PITCH)    // ushorts per buffer
#define NTHREADS 128
#define NBLOCKS (16 * NHB * NSPLIT)   // 896 = 8 XCDs x 112

typedef short s16x8 __attribute__((ext_vector_type(8)));
typedef float f32x4 __attribute__((ext_vector_type(4)));

__device__ __forceinline__ unsigned short f2bf(float f) {
  unsigned int u = __float_as_uint(f);
  u = (u + 0x7FFFu + ((u >> 16) & 1u)) >> 16;   // RNE truncate to bf16
  return (unsigned short)u;
}

__device__ __forceinline__ unsigned cvtpk(float lo, float hi) {
  unsigned r;
  asm("v_cvt_pk_bf16_f32 %0, %1, %2" : "=v"(r) : "v"(lo), "v"(hi));
  return r;   // bits[15:0]=bf16(lo), bits[31:16]=bf16(hi)
}

__global__ __launch_bounds__(256) void init_out_kernel(float* __restrict__ out,
                                                       const float* __restrict__ bias,
                                                       int n) {
  int i = blockIdx.x * 256 + threadIdx.x;
  if (i < n) out[i] = bias[0];
}

// Build Toeplitz B in fragment order: bws[((c*6+t)*64+l)*8+e] = B[kk(t,l,e)][j(l)]
__global__ __launch_bounds__(256) void build_b_kernel(const float* __restrict__ w,
                                                      unsigned short* __restrict__ bws) {
  int i = blockIdx.x * 256 + threadIdx.x;
  if (i >= C_IN * NCHUNK * 64) return;
  int l = i & 63;
  int t = (i >> 6) % NCHUNK;
  int c = i / (NCHUNK * 64);
  int q = l >> 4, j = l & 15;
  unsigned short v[8];
  #pragma unroll
  for (int e = 0; e < 8; ++e) {
    int kk = t * 32 + q * 8 + e;
    int kh = kk / 24, s = kk - kh * 24;
    int kw = s - j;
    float val = (kh < KS && kw >= 0 && kw < KS) ? w[(c * KS + kh) * KS + kw] : 0.f;
    v[e] = f2bf(val);
  }
  uint4 pk;
  pk.x = (unsigned)v[0] | ((unsigned)v[1] << 16);
  pk.y = (unsigned)v[2] | ((unsigned)v[3] << 16);
  pk.z = (unsigned)v[4] | ((unsigned)v[5] << 16);
  pk.w = (unsigned)v[6] | ((unsigned)v[7] << 16);
  *reinterpret_cast<uint4*>(bws + (size_t)i * 8) = pk;
}

__global__ __launch_bounds__(NTHREADS, 3) void conv_mfma_kernel(
    const float* __restrict__ x, const unsigned short* __restrict__ bws,
    float* __restrict__ out) {
  __shared__ unsigned short tile[2][LDSE];

  const int tid = threadIdx.x;
  const int bid = blockIdx.x;
  // XCD swizzle: HW XCD = bid%8. XCD g owns 8 (b,cs) pairs, all 14 bands each.
  const int g    = bid & 7;
  const int slot = bid >> 3;       // 0..111
  const int hb   = slot % NHB;     // 0..13
  const int pl   = slot / NHB;     // 0..7
  const int pc   = g * 8 + pl;     // 0..63 = b*NSPLIT + cs
  const int cs   = pc & (NSPLIT - 1);
  const int b    = pc >> 2;
  const int h0 = hb * TH;
  const int c0 = cs * CPB;

  // zero all of LDS once: pad rows/cols must stay finite-zero forever
  {
    uint4 z; z.x = z.y = z.z = z.w = 0u;
    for (int i = tid; i < 2 * LDSE / 8; i += NTHREADS)
      reinterpret_cast<uint4*>(&tile[0][0])[i] = z;
  }

  const int ln = tid & 63;
  const int wv = tid >> 6;   // wave id: j-blocks [wv*7, wv*7+7)
  const int q  = ln >> 4;
  const int m  = ln & 15;

  // per-chunk A byte offsets within a buffer: row (m+kh0), col s0 (kk0 = 32t+8q)
  int aoff[NCHUNK];
  #pragma unroll
  for (int t = 0; t < NCHUNK; ++t) {
    int k0 = t * 32 + q * 8;
    int kh0 = k0 / 24;
    int s0 = k0 - kh0 * 24;
    aoff[t] = (m + kh0) * (PITCH * 2) + s0 * 2;
  }

  // staging slots: 22 rows x 28 (16B bf16 groups) = 616 slots over 128 threads
  int goff[5]; int wboff[5]; bool sval[5];
  #pragma unroll
  for (int i = 0; i < 5; ++i) {
    int f = tid + NTHREADS * i;
    sval[i] = (f < 22 * 28);
    int r = sval[i] ? (f / 28) : 0;
    int cg = sval[i] ? (f - r * 28) : 0;
    int rg = h0 + r; if (rg > Hd - 1) rg = Hd - 1;   // clamp: zeros/mask cover it
    goff[i]  = rg * Wd + cg * 8;
    wboff[i] = r * (PITCH * 2) + cg * 16;
  }

  const float* xplane = x + (size_t)(b * C_IN + c0) * (Hd * Wd);

  float4 xa[5], xb[5];
  #pragma unroll
  for (int i = 0; i < 5; ++i) if (sval[i]) {
    xa[i] = *reinterpret_cast<const float4*>(xplane + goff[i]);
    xb[i] = *reinterpret_cast<const float4*>(xplane + goff[i] + 4);
  }

  f32x4 acc[7];
  #pragma unroll
  for (int jj = 0; jj < 7; ++jj) acc[jj] = (f32x4){0.f, 0.f, 0.f, 0.f};

  __syncthreads();   // zero-init visible before first ds_write

  int p = 0;
  for (int cc = 0; cc < CPB; ++cc) {
    // B fragments for this channel (coalesced 16B/lane, L2-resident 1.5MB)
    s16x8 bfr[NCHUNK];
    {
      const unsigned short* bp = bws + ((size_t)(c0 + cc) * NCHUNK * 64 + ln) * 8;
      #pragma unroll
      for (int t = 0; t < NCHUNK; ++t)
        bfr[t] = *reinterpret_cast<const s16x8*>(bp + t * 512);
    }
    // convert staged fp32 -> bf16 (HW packed cvt), write LDS buf p
    #pragma unroll
    for (int i = 0; i < 5; ++i) if (sval[i]) {
      uint4 v;
      v.x = cvtpk(xa[i].x, xa[i].y);
      v.y = cvtpk(xa[i].z, xa[i].w);
      v.z = cvtpk(xb[i].x, xb[i].y);
      v.w = cvtpk(xb[i].z, xb[i].w);
      *reinterpret_cast<uint4*>(reinterpret_cast<char*>(&tile[p][0]) + wboff[i]) = v;
    }
    // issue next channel's global loads (latency hides under compute)
    if (cc + 1 < CPB) {
      const float* xn = xplane + (size_t)(cc + 1) * (Hd * Wd);
      #pragma unroll
      for (int i = 0; i < 5; ++i) if (sval[i]) {
        xa[i] = *reinterpret_cast<const float4*>(xn + goff[i]);
        xb[i] = *reinterpret_cast<const float4*>(xn + goff[i] + 4);
      }
    }
    __syncthreads();

    const char* base = reinterpret_cast<const char*>(&tile[p][0]);
    #pragma unroll
    for (int jj = 0; jj < 7; ++jj) {
      const int cb = (wv * 7 + jj) * 32;   // w0*2 bytes
      #pragma unroll
      for (int t = 0; t < NCHUNK; ++t) {
        s16x8 a = *reinterpret_cast<const s16x8*>(base + (aoff[t] + cb));
        acc[jj] = __builtin_amdgcn_mfma_f32_16x16x32_bf16(a, bfr[t], acc[jj], 0, 0, 0);
      }
    }
    p ^= 1;
  }

  // D layout: col = lane&15, row = (lane>>4)*4 + reg
  const size_t ob = (size_t)b * (OHd * OWd);
  const int oh_base = h0 + q * 4;
  #pragma unroll
  for (int jj = 0; jj < 7; ++jj) {
    const int ow = (wv * 7 + jj) * 16 + m;
    if (ow < OWd) {
      #pragma unroll
      for (int r = 0; r < 4; ++r) {
        const int oh = oh_base + r;
        if (oh < OHd)
          atomicAdd(out + ob + (size_t)oh * OWd + ow, acc[jj][r]);
      }
    }
  }
}

extern "C" void kernel_launch(void* const* d_in, const int* in_sizes, int n_in,
                              void* d_out, int out_size, void* d_ws, size_t ws_size,
                              hipStream_t stream) {
  const float* x    = (const float*)d_in[0];
  const float* w    = (const float*)d_in[1];
  const float* bias = (const float*)d_in[2];
  float* out        = (float*)d_out;
  unsigned short* bws = (unsigned short*)d_ws;   // needs 1.57 MB

  init_out_kernel<<<(out_size + 255) / 256, 256, 0, stream>>>(out, bias, out_size);
  build_b_kernel<<<(C_IN * NCHUNK * 64 + 255) / 256, 256, 0, stream>>>(w, bws);
  conv_mfma_kernel<<<NBLOCKS, NTHREADS, 0, stream>>>(x, bws, out);
}